// Round 1
// baseline (717.436 us; speedup 1.0000x reference)
//
#include <hip/hip_runtime.h>

#define NB 16
#define NC 768
#define NT 512
#define NH 1536
#define KS 384
#define NPX 4096

typedef __bf16 bfx8 __attribute__((ext_vector_type(8)));
typedef float fx4 __attribute__((ext_vector_type(4)));
typedef unsigned short u16;
typedef unsigned short usv4 __attribute__((ext_vector_type(4)));

__device__ __forceinline__ u16 f2bf(float f) {
  unsigned u = __builtin_bit_cast(unsigned, f);
  u += 0x7FFFu + ((u >> 16) & 1u);
  return (u16)(u >> 16);
}

// ---- K1: transpose x -> bf16 xT[b][px][c], and partial column sums ----
__global__ void k_trans_mean(const float* __restrict__ x, u16* __restrict__ xT,
                             float* __restrict__ parts) {
  __shared__ float ld[64][65];
  int p0 = blockIdx.x * 64, c0 = blockIdx.y * 64, b = blockIdx.z;
  int t = threadIdx.x;
#pragma unroll
  for (int s = 0; s < 16; ++s) {
    int id = t + 256 * s;
    int i = id >> 6, j = id & 63;
    ld[i][j] = x[(size_t)(b * NC + c0 + i) * NPX + p0 + j];
  }
  __syncthreads();
#pragma unroll
  for (int s = 0; s < 16; ++s) {
    int id = t + 256 * s;
    int j = id >> 6, i = id & 63;
    xT[(size_t)(b * NPX + p0 + j) * NC + c0 + i] = f2bf(ld[i][j]);
  }
  if (t < 64) {
    float s = 0.f;
    for (int j = 0; j < 64; ++j) s += ld[t][j];
    parts[(size_t)(b * NC + c0 + t) * 64 + blockIdx.x] = s;
  }
}

__global__ void k_mean_fin(const float* __restrict__ parts, float* __restrict__ xmean) {
  int id = blockIdx.x * 256 + threadIdx.x;
  if (id >= NB * NC) return;
  float s = 0.f;
  for (int j = 0; j < 64; ++j) s += parts[(size_t)id * 64 + j];
  xmean[id] = s * (1.f / 4096.f);
}

__global__ void k_silu(const float* __restrict__ temb, float* __restrict__ st) {
  int id = blockIdx.x * 256 + threadIdx.x;
  if (id < NB * NT) { float v = temb[id]; st[id] = v / (1.f + expf(-v)); }
}

// ---- small batched MLP: Y[b][obase+j] = (silu?)(dot(W[j,:], X[b,:]) + bias[j]), 8 batches/block ----
__global__ void k_mlp8(const float* __restrict__ W, const float* __restrict__ bias,
                       const float* __restrict__ X, float* __restrict__ Y,
                       int len, int nj, int ostride, int obase, int dosilu) {
  __shared__ float Xs[8 * 1537];
  int t = threadIdx.x, lane = t & 63, w = t >> 6;
  int b0 = blockIdx.y * 8;
  int ldx = len + 1;
  for (int id = t; id < 8 * len; id += 256) {
    int bb = id / len, s = id - bb * len;
    Xs[bb * ldx + s] = X[(size_t)(b0 + bb) * len + s];
  }
  __syncthreads();
  for (int i = 0; i < 4; ++i) {
    int j = blockIdx.x * 16 + i * 4 + w;
    if (j < nj) {
      float acc[8] = {0, 0, 0, 0, 0, 0, 0, 0};
      for (int s = lane; s < len; s += 64) {
        float wv = W[(size_t)j * len + s];
#pragma unroll
        for (int bb = 0; bb < 8; ++bb) acc[bb] += wv * Xs[bb * ldx + s];
      }
#pragma unroll
      for (int bb = 0; bb < 8; ++bb) {
        float r = acc[bb];
#pragma unroll
        for (int m = 32; m; m >>= 1) r += __shfl_xor(r, m);
        if (lane == 0) {
          r += bias[j];
          if (dosilu) r = r / (1.f + expf(-r));
          Y[(size_t)(b0 + bb) * ostride + obase + j] = r;
        }
      }
    }
  }
}

// ---- p = [gap, tp]; gap = xmean*(1+scale)+shift ----
__global__ void k_assemble_p(const float* __restrict__ Y1, const float* __restrict__ xmean,
                             float* __restrict__ p) {
  int id = blockIdx.x * 256 + threadIdx.x;
  if (id >= NB * NC) return;
  int b = id / NC, c = id - b * NC;
  const float* yb = Y1 + (size_t)b * 2304;
  p[(size_t)b * 1536 + c] = xmean[id] * (1.f + yb[c]) + yb[768 + c];
  p[(size_t)b * 1536 + 768 + c] = yb[1536 + c];
}

// ---- top-k by rank counting (set-exact, deterministic) ----
__global__ void k_topk(const float* __restrict__ prompt, int* __restrict__ idx) {
  __shared__ float pr[NC];
  int b = blockIdx.x, t = threadIdx.x;
  for (int c = t; c < NC; c += 256) pr[c] = prompt[(size_t)b * NC + c];
  __syncthreads();
  for (int c = t; c < NC; c += 256) {
    float v = pr[c];
    int r = 0;
    for (int c2 = 0; c2 < NC; ++c2) {
      float v2 = pr[c2];
      r += (v2 > v) || (v2 == v && c2 < c);
    }
    if (r < KS) idx[b * KS + r] = c;
  }
}

// ---- fold scale into gathered qkv weight rows; shift into bias ----
__global__ void k_fold(const int* __restrict__ idx, const float* __restrict__ Y1,
                       const float* __restrict__ Wq, const float* __restrict__ bq,
                       const float* __restrict__ Wk, const float* __restrict__ bk,
                       const float* __restrict__ Wv, const float* __restrict__ bv,
                       u16* __restrict__ Aq, float* __restrict__ biasq) {
  __shared__ float red[3 * 256];
  int k = blockIdx.x, b = blockIdx.y, t = threadIdx.x;
  int row = idx[b * KS + k];
  const float* yb = Y1 + (size_t)b * 2304;
  u16* aq = Aq + (size_t)b * 1152 * NC;
  float dq = 0.f, dk = 0.f, dv = 0.f;
  for (int c = t; c < NC; c += 256) {
    float sc = 1.f + yb[c], sh = yb[768 + c];
    float wq = Wq[(size_t)row * NC + c];
    float wk = Wk[(size_t)row * NC + c];
    float wv = Wv[(size_t)row * NC + c];
    aq[(size_t)k * NC + c] = f2bf(wq * sc);
    aq[(size_t)(KS + k) * NC + c] = f2bf(wk * sc);
    aq[(size_t)(2 * KS + k) * NC + c] = f2bf(wv * sc);
    dq += wq * sh; dk += wk * sh; dv += wv * sh;
  }
  red[t] = dq; red[256 + t] = dk; red[512 + t] = dv;
  __syncthreads();
  for (int s = 128; s; s >>= 1) {
    if (t < s) {
      red[t] += red[t + s];
      red[256 + t] += red[256 + t + s];
      red[512 + t] += red[512 + t + s];
    }
    __syncthreads();
  }
  if (t == 0) {
    biasq[b * 1152 + k] = bq[row] + red[0];
    biasq[b * 1152 + KS + k] = bk[row] + red[256];
    biasq[b * 1152 + 2 * KS + k] = bv[row] + red[512];
  }
}

// ---- gather Wo columns: WoSel[b][o][k] = Wo[o][idx[b][k]] ----
__global__ void k_gather_wo(const int* __restrict__ idx, const float* __restrict__ Wo,
                            u16* __restrict__ WoSel) {
  __shared__ int il[KS];
  int b = blockIdx.y, t = threadIdx.x;
  for (int k = t; k < KS; k += 256) il[k] = idx[b * KS + k];
  __syncthreads();
  int o0 = blockIdx.x * 8;
  for (int oo = 0; oo < 8; ++oo) {
    int o = o0 + oo;
    const float* wr = Wo + (size_t)o * NC;
    u16* dst = WoSel + ((size_t)b * NC + o) * KS;
    for (int k = t; k < KS; k += 256) dst[k] = f2bf(wr[il[k]]);
  }
}

// ---- row softmax of S[b][k][:], write transposed bf16 At[b][l][k] ----
__global__ void k_softmax(const float* __restrict__ S, u16* __restrict__ At) {
  __shared__ float sh[2];
  int kk = blockIdx.x, b = blockIdx.y, t = threadIdx.x; // 128 threads
  const float* srow = S + ((size_t)b * KS + kk) * KS;
  float v[3];
#pragma unroll
  for (int i = 0; i < 3; ++i) v[i] = srow[t + 128 * i];
  float m = fmaxf(fmaxf(v[0], v[1]), v[2]);
#pragma unroll
  for (int s = 32; s; s >>= 1) m = fmaxf(m, __shfl_xor(m, s));
  if ((t & 63) == 0) sh[t >> 6] = m;
  __syncthreads();
  m = fmaxf(sh[0], sh[1]);
  float e[3];
  float sum = 0.f;
#pragma unroll
  for (int i = 0; i < 3; ++i) { e[i] = expf(v[i] - m); sum += e[i]; }
#pragma unroll
  for (int s = 32; s; s >>= 1) sum += __shfl_xor(sum, s);
  __syncthreads();
  if ((t & 63) == 0) sh[t >> 6] = sum;
  __syncthreads();
  sum = sh[0] + sh[1];
  float inv = 1.f / sum;
#pragma unroll
  for (int i = 0; i < 3; ++i) {
    int l = t + 128 * i;
    At[((size_t)b * KS + l) * KS + kk] = f2bf(e[i] * inv);
  }
}

// ---- GEMM C = A @ Bt^T, A[M,K] rm bf16, Bt[N,K] rm bf16, batched by blockIdx.z ----
#define LDK 72

template <int EPI>
__global__ __launch_bounds__(256, 2) void gemm_bt(
    const u16* __restrict__ A, const u16* __restrict__ Bt, size_t sA, size_t sB,
    int ldA, int ldB, int K, const float* __restrict__ bias,
    float* __restrict__ outF, u16* __restrict__ outU, u16* __restrict__ outU2, float scale) {
  __shared__ u16 As[128 * LDK];
  __shared__ u16 Bs[128 * LDK];
  int b = blockIdx.z;
  int m0 = blockIdx.y * 128, n0 = blockIdx.x * 128;
  const u16* Ab = A + (size_t)b * sA;
  const u16* Bb = Bt + (size_t)b * sB;
  int t = threadIdx.x, lane = t & 63, w = t >> 6;
  int wm = (w >> 1) * 64, wn = (w & 1) * 64;
  int r16 = lane & 15, g = lane >> 4;

  fx4 acc[4][4] = {};

  for (int k0 = 0; k0 < K; k0 += 64) {
#pragma unroll
    for (int s = 0; s < 4; ++s) {
      int id = t + 256 * s;
      int row = id >> 3, c8 = (id & 7) * 8;
      *(int4*)&As[row * LDK + c8] = *(const int4*)(Ab + (size_t)(m0 + row) * ldA + k0 + c8);
      *(int4*)&Bs[row * LDK + c8] = *(const int4*)(Bb + (size_t)(n0 + row) * ldB + k0 + c8);
    }
    __syncthreads();
#pragma unroll
    for (int kk = 0; kk < 2; ++kk) {
      bfx8 af[4], bfr[4];
#pragma unroll
      for (int i = 0; i < 4; ++i) {
        af[i] = *(const bfx8*)&As[(wm + i * 16 + r16) * LDK + kk * 32 + g * 8];
        bfr[i] = *(const bfx8*)&Bs[(wn + i * 16 + r16) * LDK + kk * 32 + g * 8];
      }
#pragma unroll
      for (int i = 0; i < 4; ++i)
#pragma unroll
        for (int j = 0; j < 4; ++j)
          acc[i][j] = __builtin_amdgcn_mfma_f32_16x16x32_bf16(af[i], bfr[j], acc[i][j], 0, 0, 0);
    }
    __syncthreads();
  }

#pragma unroll
  for (int i = 0; i < 4; ++i) {
#pragma unroll
    for (int j = 0; j < 4; ++j) {
      int row = m0 + wm + i * 16 + g * 4;
      int col = n0 + wn + j * 16 + r16;
      fx4 v = acc[i][j];
      if constexpr (EPI == 0) {  // qkv: rows<768 -> qk[b][row][col]; rows>=768 -> vT[b][col][row-768]
        const float* bi = bias + b * 1152;
        if (row < 768) {
#pragma unroll
          for (int r = 0; r < 4; ++r)
            outU[((size_t)b * 768 + row + r) * 4096 + col] = f2bf(v[r] + bi[row + r]);
        } else {
          usv4 pk;
#pragma unroll
          for (int r = 0; r < 4; ++r) pk[r] = f2bf(v[r] + bi[row + r]);
          *(usv4*)&outU2[((size_t)b * 4096 + col) * 384 + (row - 768)] = pk;
        }
      } else if constexpr (EPI == 1) {  // S fp32 * scale
#pragma unroll
        for (int r = 0; r < 4; ++r)
          outF[((size_t)b * 384 + row + r) * 384 + col] = v[r] * scale;
      } else if constexpr (EPI == 2) {  // M bf16
#pragma unroll
        for (int r = 0; r < 4; ++r)
          outU[((size_t)b * 768 + row + r) * 384 + col] = f2bf(v[r]);
      } else {  // final fp32 + bo
#pragma unroll
        for (int r = 0; r < 4; ++r)
          outF[((size_t)b * 768 + row + r) * 4096 + col] = v[r] + bias[row + r];
      }
    }
  }
}

__global__ void k_sentinel(float* out, int n) {
  int id = blockIdx.x * 256 + threadIdx.x;
  if (id < n) out[id] = 12345.0f;
}

extern "C" void kernel_launch(void* const* d_in, const int* in_sizes, int n_in,
                              void* d_out, int out_size, void* d_ws, size_t ws_size,
                              hipStream_t stream) {
  const float* x    = (const float*)d_in[0];
  const float* temb = (const float*)d_in[1];
  const float* W_ts = (const float*)d_in[2];
  const float* b_ts = (const float*)d_in[3];
  const float* W_tp = (const float*)d_in[4];
  const float* b_tp = (const float*)d_in[5];
  const float* W_m1 = (const float*)d_in[6];
  const float* b_m1 = (const float*)d_in[7];
  const float* W_m2 = (const float*)d_in[8];
  const float* b_m2 = (const float*)d_in[9];
  const float* Wq = (const float*)d_in[10];
  const float* bq = (const float*)d_in[11];
  const float* Wk = (const float*)d_in[12];
  const float* bk = (const float*)d_in[13];
  const float* Wv = (const float*)d_in[14];
  const float* bv = (const float*)d_in[15];
  const float* Wo = (const float*)d_in[16];
  const float* bo = (const float*)d_in[17];
  float* out = (float*)d_out;

  char* base = (char*)d_ws;
  size_t off = 0;
  auto alloc = [&](size_t bytes) -> char* {
    char* pp = base + off;
    off += (bytes + 255) & ~(size_t)255;
    return pp;
  };
  u16* xT     = (u16*)alloc((size_t)NB * NPX * NC * 2);      // 100.7 MB (reused for S/At/Mm after QKV gemm)
  u16* qk     = (u16*)alloc((size_t)NB * 768 * NPX * 2);     // 100.7 MB
  u16* vT     = (u16*)alloc((size_t)NB * NPX * KS * 2);      // 50.3 MB
  u16* Aq     = (u16*)alloc((size_t)NB * 1152 * NC * 2);     // 28.3 MB
  u16* WoS    = (u16*)alloc((size_t)NB * NC * KS * 2);       // 9.4 MB
  float* parts  = (float*)alloc((size_t)NB * NC * 64 * 4);
  float* xmean  = (float*)alloc((size_t)NB * NC * 4);
  float* Y1     = (float*)alloc((size_t)NB * 2304 * 4);
  float* st     = (float*)alloc((size_t)NB * NT * 4);
  float* p      = (float*)alloc((size_t)NB * 1536 * 4);
  float* hid    = (float*)alloc((size_t)NB * 1536 * 4);
  float* pr     = (float*)alloc((size_t)NB * NC * 4);
  int*   idx    = (int*)alloc((size_t)NB * KS * 4);
  float* biasq  = (float*)alloc((size_t)NB * 1152 * 4);

  if (off > ws_size) {  // diagnosable failure: absmax ~12345
    k_sentinel<<<(out_size + 255) / 256, 256, 0, stream>>>(out, out_size);
    return;
  }

  // overlay attention temporaries on xT (dead after gemm<0>)
  float* S = (float*)xT;
  u16* At  = (u16*)((char*)xT + 16u * 1024 * 1024);
  u16* Mm  = (u16*)((char*)xT + 24u * 1024 * 1024);

  k_trans_mean<<<dim3(64, 12, NB), 256, 0, stream>>>(x, xT, parts);
  k_mean_fin<<<(NB * NC + 255) / 256, 256, 0, stream>>>(parts, xmean);
  k_silu<<<(NB * NT + 255) / 256, 256, 0, stream>>>(temb, st);
  k_mlp8<<<dim3(96, 2), 256, 0, stream>>>(W_ts, b_ts, st, Y1, 512, 1536, 2304, 0, 0);
  k_mlp8<<<dim3(48, 2), 256, 0, stream>>>(W_tp, b_tp, st, Y1, 512, 768, 2304, 1536, 0);
  k_assemble_p<<<(NB * NC + 255) / 256, 256, 0, stream>>>(Y1, xmean, p);
  k_mlp8<<<dim3(96, 2), 256, 0, stream>>>(W_m1, b_m1, p, hid, 1536, 1536, 1536, 0, 1);
  k_mlp8<<<dim3(48, 2), 256, 0, stream>>>(W_m2, b_m2, hid, pr, 1536, 768, 768, 0, 0);
  k_topk<<<NB, 256, 0, stream>>>(pr, idx);
  k_fold<<<dim3(KS, NB), 256, 0, stream>>>(idx, Y1, Wq, bq, Wk, bk, Wv, bv, Aq, biasq);
  k_gather_wo<<<dim3(96, NB), 256, 0, stream>>>(idx, Wo, WoS);

  // qkv: [1152,768] x [768,4096]^T(from xT[4096,768])
  gemm_bt<0><<<dim3(32, 9, NB), 256, 0, stream>>>(
      Aq, xT, (size_t)1152 * NC, (size_t)NPX * NC, NC, NC, NC, biasq, nullptr, qk, vT, 0.f);
  // S = q @ k^T * K^-0.5
  gemm_bt<1><<<dim3(3, 3, NB), 256, 0, stream>>>(
      qk, qk + (size_t)KS * NPX, (size_t)768 * NPX, (size_t)768 * NPX, NPX, NPX, NPX,
      nullptr, S, nullptr, nullptr, 0.05103103630798287f);
  k_softmax<<<dim3(KS, NB), 128, 0, stream>>>(S, At);
  // M = WoSel @ attn   (via At = attn^T)
  gemm_bt<2><<<dim3(3, 6, NB), 256, 0, stream>>>(
      WoS, At, (size_t)NC * KS, (size_t)KS * KS, KS, KS, KS, nullptr, nullptr, Mm, nullptr, 0.f);
  // out = M @ v + bo   (via vT)
  gemm_bt<3><<<dim3(32, 6, NB), 256, 0, stream>>>(
      Mm, vT, (size_t)NC * KS, (size_t)NPX * KS, KS, KS, KS, bo, out, nullptr, nullptr, 0.f);
}

// Round 2
// 642.442 us; speedup vs baseline: 1.1167x; 1.1167x over previous
//
#include <hip/hip_runtime.h>

#define NB 16
#define NC 768
#define NT 512
#define NH 1536
#define KS 384
#define NPX 4096
#define BK 64

typedef __bf16 bfx8 __attribute__((ext_vector_type(8)));
typedef float fx4 __attribute__((ext_vector_type(4)));
typedef unsigned short u16;
typedef unsigned short usv4 __attribute__((ext_vector_type(4)));

__device__ __forceinline__ u16 f2bf(float f) {
  unsigned u = __builtin_bit_cast(unsigned, f);
  u += 0x7FFFu + ((u >> 16) & 1u);
  return (u16)(u >> 16);
}

__device__ __forceinline__ void gload16(const u16* g, u16* l) {
  __builtin_amdgcn_global_load_lds(
      (const __attribute__((address_space(1))) unsigned int*)g,
      (__attribute__((address_space(3))) unsigned int*)l, 16, 0, 0);
}

// ---- K1: transpose x -> bf16 xT[b][px][c], and partial column sums ----
__global__ void k_trans_mean(const float* __restrict__ x, u16* __restrict__ xT,
                             float* __restrict__ parts) {
  __shared__ float ld[64][65];
  int p0 = blockIdx.x * 64, c0 = blockIdx.y * 64, b = blockIdx.z;
  int t = threadIdx.x;
#pragma unroll
  for (int s = 0; s < 16; ++s) {
    int id = t + 256 * s;
    int i = id >> 6, j = id & 63;
    ld[i][j] = x[(size_t)(b * NC + c0 + i) * NPX + p0 + j];
  }
  __syncthreads();
#pragma unroll
  for (int s = 0; s < 16; ++s) {
    int id = t + 256 * s;
    int j = id >> 6, i = id & 63;
    xT[(size_t)(b * NPX + p0 + j) * NC + c0 + i] = f2bf(ld[i][j]);
  }
  if (t < 64) {
    float s = 0.f;
    for (int j = 0; j < 64; ++j) s += ld[t][j];
    parts[(size_t)(b * NC + c0 + t) * 64 + blockIdx.x] = s;
  }
}

__global__ void k_mean_fin(const float* __restrict__ parts, float* __restrict__ xmean) {
  int id = blockIdx.x * 256 + threadIdx.x;
  if (id >= NB * NC) return;
  float s = 0.f;
  for (int j = 0; j < 64; ++j) s += parts[(size_t)id * 64 + j];
  xmean[id] = s * (1.f / 4096.f);
}

__global__ void k_silu(const float* __restrict__ temb, float* __restrict__ st) {
  int id = blockIdx.x * 256 + threadIdx.x;
  if (id < NB * NT) { float v = temb[id]; st[id] = v / (1.f + expf(-v)); }
}

// ---- small batched MLP ----
__global__ void k_mlp8(const float* __restrict__ W, const float* __restrict__ bias,
                       const float* __restrict__ X, float* __restrict__ Y,
                       int len, int nj, int ostride, int obase, int dosilu) {
  __shared__ float Xs[8 * 1537];
  int t = threadIdx.x, lane = t & 63, w = t >> 6;
  int b0 = blockIdx.y * 8;
  int ldx = len + 1;
  for (int id = t; id < 8 * len; id += 256) {
    int bb = id / len, s = id - bb * len;
    Xs[bb * ldx + s] = X[(size_t)(b0 + bb) * len + s];
  }
  __syncthreads();
  for (int i = 0; i < 4; ++i) {
    int j = blockIdx.x * 16 + i * 4 + w;
    if (j < nj) {
      float acc[8] = {0, 0, 0, 0, 0, 0, 0, 0};
      for (int s = lane; s < len; s += 64) {
        float wv = W[(size_t)j * len + s];
#pragma unroll
        for (int bb = 0; bb < 8; ++bb) acc[bb] += wv * Xs[bb * ldx + s];
      }
#pragma unroll
      for (int bb = 0; bb < 8; ++bb) {
        float r = acc[bb];
#pragma unroll
        for (int m = 32; m; m >>= 1) r += __shfl_xor(r, m);
        if (lane == 0) {
          r += bias[j];
          if (dosilu) r = r / (1.f + expf(-r));
          Y[(size_t)(b0 + bb) * ostride + obase + j] = r;
        }
      }
    }
  }
}

// ---- p = [gap, tp]; gap = xmean*(1+scale)+shift ----
__global__ void k_assemble_p(const float* __restrict__ Y1, const float* __restrict__ xmean,
                             float* __restrict__ p) {
  int id = blockIdx.x * 256 + threadIdx.x;
  if (id >= NB * NC) return;
  int b = id / NC, c = id - b * NC;
  const float* yb = Y1 + (size_t)b * 2304;
  p[(size_t)b * 1536 + c] = xmean[id] * (1.f + yb[c]) + yb[768 + c];
  p[(size_t)b * 1536 + 768 + c] = yb[1536 + c];
}

// ---- top-k by rank counting (set-exact, deterministic) ----
__global__ void k_topk(const float* __restrict__ prompt, int* __restrict__ idx) {
  __shared__ float pr[NC];
  int b = blockIdx.x, t = threadIdx.x;
  for (int c = t; c < NC; c += 256) pr[c] = prompt[(size_t)b * NC + c];
  __syncthreads();
  for (int c = t; c < NC; c += 256) {
    float v = pr[c];
    int r = 0;
    for (int c2 = 0; c2 < NC; ++c2) {
      float v2 = pr[c2];
      r += (v2 > v) || (v2 == v && c2 < c);
    }
    if (r < KS) idx[b * KS + r] = c;
  }
}

// ---- fold scale into gathered qkv weight rows; shift into bias ----
__global__ void k_fold(const int* __restrict__ idx, const float* __restrict__ Y1,
                       const float* __restrict__ Wq, const float* __restrict__ bq,
                       const float* __restrict__ Wk, const float* __restrict__ bk,
                       const float* __restrict__ Wv, const float* __restrict__ bv,
                       u16* __restrict__ Aq, float* __restrict__ biasq) {
  __shared__ float red[3 * 256];
  int k = blockIdx.x, b = blockIdx.y, t = threadIdx.x;
  int row = idx[b * KS + k];
  const float* yb = Y1 + (size_t)b * 2304;
  u16* aq = Aq + (size_t)b * 1152 * NC;
  float dq = 0.f, dk = 0.f, dv = 0.f;
  for (int c = t; c < NC; c += 256) {
    float sc = 1.f + yb[c], sh = yb[768 + c];
    float wq = Wq[(size_t)row * NC + c];
    float wk = Wk[(size_t)row * NC + c];
    float wv = Wv[(size_t)row * NC + c];
    aq[(size_t)k * NC + c] = f2bf(wq * sc);
    aq[(size_t)(KS + k) * NC + c] = f2bf(wk * sc);
    aq[(size_t)(2 * KS + k) * NC + c] = f2bf(wv * sc);
    dq += wq * sh; dk += wk * sh; dv += wv * sh;
  }
  red[t] = dq; red[256 + t] = dk; red[512 + t] = dv;
  __syncthreads();
  for (int s = 128; s; s >>= 1) {
    if (t < s) {
      red[t] += red[t + s];
      red[256 + t] += red[256 + t + s];
      red[512 + t] += red[512 + t + s];
    }
    __syncthreads();
  }
  if (t == 0) {
    biasq[b * 1152 + k] = bq[row] + red[0];
    biasq[b * 1152 + KS + k] = bk[row] + red[256];
    biasq[b * 1152 + 2 * KS + k] = bv[row] + red[512];
  }
}

// ---- gather Wo columns: WoSel[b][o][k] = Wo[o][idx[b][k]] ----
__global__ void k_gather_wo(const int* __restrict__ idx, const float* __restrict__ Wo,
                            u16* __restrict__ WoSel) {
  __shared__ int il[KS];
  int b = blockIdx.y, t = threadIdx.x;
  for (int k = t; k < KS; k += 256) il[k] = idx[b * KS + k];
  __syncthreads();
  int o0 = blockIdx.x * 8;
  for (int oo = 0; oo < 8; ++oo) {
    int o = o0 + oo;
    const float* wr = Wo + (size_t)o * NC;
    u16* dst = WoSel + ((size_t)b * NC + o) * KS;
    for (int k = t; k < KS; k += 256) dst[k] = f2bf(wr[il[k]]);
  }
}

// ---- row softmax: sums 4 split-K partials, writes transposed bf16 At[b][l][k] ----
__global__ void k_softmax(const float* __restrict__ Sp, u16* __restrict__ At) {
  __shared__ float sh[2];
  int kk = blockIdx.x, b = blockIdx.y, t = threadIdx.x; // 128 threads
  const size_t stride = (size_t)NB * KS * KS;
  const float* srow = Sp + ((size_t)b * KS + kk) * KS;
  float v[3];
#pragma unroll
  for (int i = 0; i < 3; ++i) {
    int l = t + 128 * i;
    v[i] = srow[l] + srow[stride + l] + srow[2 * stride + l] + srow[3 * stride + l];
  }
  float m = fmaxf(fmaxf(v[0], v[1]), v[2]);
#pragma unroll
  for (int s = 32; s; s >>= 1) m = fmaxf(m, __shfl_xor(m, s));
  if ((t & 63) == 0) sh[t >> 6] = m;
  __syncthreads();
  m = fmaxf(sh[0], sh[1]);
  float e[3];
  float sum = 0.f;
#pragma unroll
  for (int i = 0; i < 3; ++i) { e[i] = expf(v[i] - m); sum += e[i]; }
#pragma unroll
  for (int s = 32; s; s >>= 1) sum += __shfl_xor(sum, s);
  __syncthreads();
  if ((t & 63) == 0) sh[t >> 6] = sum;
  __syncthreads();
  sum = sh[0] + sh[1];
  float inv = 1.f / sum;
#pragma unroll
  for (int i = 0; i < 3; ++i) {
    int l = t + 128 * i;
    At[((size_t)b * KS + l) * KS + kk] = f2bf(e[i] * inv);
  }
}

// ---- GEMM C = A @ Bt^T via global_load_lds staging (m97 structure) ----
template <int EPI>
__global__ __launch_bounds__(256, 2) void gemm_bt(
    const u16* __restrict__ A, const u16* __restrict__ Bt, size_t sA, size_t sB,
    int ldA, int ldB, int K, int ksplit, const float* __restrict__ bias,
    float* __restrict__ outF, u16* __restrict__ outU, u16* __restrict__ outU2, float scale) {
  __shared__ u16 As[128 * BK];
  __shared__ u16 Bs[128 * BK];
  int bz = blockIdx.z;
  int b = bz, kbeg = 0, kend = K;
  if (ksplit > 1) {
    b = bz / ksplit;
    int part = bz - b * ksplit;
    int kl = K / ksplit;
    kbeg = part * kl;
    kend = kbeg + kl;
    outF += (size_t)part * NB * KS * KS;
  }
  int m0 = blockIdx.y * 128, n0 = blockIdx.x * 128;
  const u16* Ab = A + (size_t)b * sA;
  const u16* Bb = Bt + (size_t)b * sB;
  int t = threadIdx.x, lane = t & 63, w = t >> 6;
  int wm = (w >> 1) * 64, wn = (w & 1) * 64;
  int r16 = lane & 15, g = lane >> 4;

  // staging: per-lane global addr, wave-uniform LDS base (+lane*16B by HW)
  int srow = w * 32 + (lane >> 3);
  int scol = (lane & 7) * 8;
  const u16* Ag = Ab + (size_t)(m0 + srow) * ldA + kbeg + scol;
  const u16* Bg = Bb + (size_t)(n0 + srow) * ldB + kbeg + scol;
  u16* Asl = &As[(w * 32) * BK];
  u16* Bsl = &Bs[(w * 32) * BK];

  fx4 acc[4][4] = {};

  for (int k0 = kbeg; k0 < kend; k0 += BK) {
#pragma unroll
    for (int s = 0; s < 4; ++s) gload16(Ag + (size_t)s * 8 * ldA, Asl + s * 8 * BK);
#pragma unroll
    for (int s = 0; s < 4; ++s) gload16(Bg + (size_t)s * 8 * ldB, Bsl + s * 8 * BK);
    Ag += BK; Bg += BK;
    __syncthreads();
#pragma unroll
    for (int kk = 0; kk < 2; ++kk) {
      bfx8 af[4], bfr[4];
#pragma unroll
      for (int i = 0; i < 4; ++i) {
        af[i] = *(const bfx8*)&As[(wm + i * 16 + r16) * BK + kk * 32 + g * 8];
        bfr[i] = *(const bfx8*)&Bs[(wn + i * 16 + r16) * BK + kk * 32 + g * 8];
      }
#pragma unroll
      for (int i = 0; i < 4; ++i)
#pragma unroll
        for (int j = 0; j < 4; ++j)
          acc[i][j] = __builtin_amdgcn_mfma_f32_16x16x32_bf16(af[i], bfr[j], acc[i][j], 0, 0, 0);
    }
    __syncthreads();
  }

#pragma unroll
  for (int i = 0; i < 4; ++i) {
#pragma unroll
    for (int j = 0; j < 4; ++j) {
      int row = m0 + wm + i * 16 + g * 4;
      int col = n0 + wn + j * 16 + r16;
      fx4 v = acc[i][j];
      if constexpr (EPI == 0) {  // qkv: rows<768 -> qk[b][row][col]; rows>=768 -> vT[b][col][row-768]
        const float* bi = bias + b * 1152;
        if (row < 768) {
#pragma unroll
          for (int r = 0; r < 4; ++r)
            outU[((size_t)b * 768 + row + r) * 4096 + col] = f2bf(v[r] + bi[row + r]);
        } else {
          usv4 pk;
#pragma unroll
          for (int r = 0; r < 4; ++r) pk[r] = f2bf(v[r] + bi[row + r]);
          *(usv4*)&outU2[((size_t)b * 4096 + col) * 384 + (row - 768)] = pk;
        }
      } else if constexpr (EPI == 1) {  // S partial fp32 * scale
#pragma unroll
        for (int r = 0; r < 4; ++r)
          outF[((size_t)b * 384 + row + r) * 384 + col] = v[r] * scale;
      } else if constexpr (EPI == 2) {  // M bf16
#pragma unroll
        for (int r = 0; r < 4; ++r)
          outU[((size_t)b * 768 + row + r) * 384 + col] = f2bf(v[r]);
      } else {  // final fp32 + bo
#pragma unroll
        for (int r = 0; r < 4; ++r)
          outF[((size_t)b * 768 + row + r) * 4096 + col] = v[r] + bias[row + r];
      }
    }
  }
}

__global__ void k_sentinel(float* out, int n) {
  int id = blockIdx.x * 256 + threadIdx.x;
  if (id < n) out[id] = 12345.0f;
}

extern "C" void kernel_launch(void* const* d_in, const int* in_sizes, int n_in,
                              void* d_out, int out_size, void* d_ws, size_t ws_size,
                              hipStream_t stream) {
  const float* x    = (const float*)d_in[0];
  const float* temb = (const float*)d_in[1];
  const float* W_ts = (const float*)d_in[2];
  const float* b_ts = (const float*)d_in[3];
  const float* W_tp = (const float*)d_in[4];
  const float* b_tp = (const float*)d_in[5];
  const float* W_m1 = (const float*)d_in[6];
  const float* b_m1 = (const float*)d_in[7];
  const float* W_m2 = (const float*)d_in[8];
  const float* b_m2 = (const float*)d_in[9];
  const float* Wq = (const float*)d_in[10];
  const float* bq = (const float*)d_in[11];
  const float* Wk = (const float*)d_in[12];
  const float* bk = (const float*)d_in[13];
  const float* Wv = (const float*)d_in[14];
  const float* bv = (const float*)d_in[15];
  const float* Wo = (const float*)d_in[16];
  const float* bo = (const float*)d_in[17];
  float* out = (float*)d_out;

  char* base = (char*)d_ws;
  size_t off = 0;
  auto alloc = [&](size_t bytes) -> char* {
    char* pp = base + off;
    off += (bytes + 255) & ~(size_t)255;
    return pp;
  };
  u16* xT     = (u16*)alloc((size_t)NB * NPX * NC * 2);      // 100.7 MB (reused for Sp/At/Mm after QKV gemm)
  u16* qk     = (u16*)alloc((size_t)NB * 768 * NPX * 2);     // 100.7 MB
  u16* vT     = (u16*)alloc((size_t)NB * NPX * KS * 2);      // 50.3 MB
  u16* Aq     = (u16*)alloc((size_t)NB * 1152 * NC * 2);     // 28.3 MB
  u16* WoS    = (u16*)alloc((size_t)NB * NC * KS * 2);       // 9.4 MB
  float* parts  = (float*)alloc((size_t)NB * NC * 64 * 4);
  float* xmean  = (float*)alloc((size_t)NB * NC * 4);
  float* Y1     = (float*)alloc((size_t)NB * 2304 * 4);
  float* st     = (float*)alloc((size_t)NB * NT * 4);
  float* p      = (float*)alloc((size_t)NB * 1536 * 4);
  float* hid    = (float*)alloc((size_t)NB * 1536 * 4);
  float* pr     = (float*)alloc((size_t)NB * NC * 4);
  int*   idx    = (int*)alloc((size_t)NB * KS * 4);
  float* biasq  = (float*)alloc((size_t)NB * 1152 * 4);

  if (off > ws_size) {  // diagnosable failure: absmax ~12345
    k_sentinel<<<(out_size + 255) / 256, 256, 0, stream>>>(out, out_size);
    return;
  }

  // overlay attention temporaries on xT (dead after gemm<0>)
  float* Sp = (float*)xT;                                    // 4 partials x 9.44 MB = 37.75 MB
  u16* At  = (u16*)((char*)xT + 40u * 1024 * 1024);          // 4.7 MB
  u16* Mm  = (u16*)((char*)xT + 48u * 1024 * 1024);          // 9.4 MB

  k_trans_mean<<<dim3(64, 12, NB), 256, 0, stream>>>(x, xT, parts);
  k_mean_fin<<<(NB * NC + 255) / 256, 256, 0, stream>>>(parts, xmean);
  k_silu<<<(NB * NT + 255) / 256, 256, 0, stream>>>(temb, st);
  k_mlp8<<<dim3(96, 2), 256, 0, stream>>>(W_ts, b_ts, st, Y1, 512, 1536, 2304, 0, 0);
  k_mlp8<<<dim3(48, 2), 256, 0, stream>>>(W_tp, b_tp, st, Y1, 512, 768, 2304, 1536, 0);
  k_assemble_p<<<(NB * NC + 255) / 256, 256, 0, stream>>>(Y1, xmean, p);
  k_mlp8<<<dim3(96, 2), 256, 0, stream>>>(W_m1, b_m1, p, hid, 1536, 1536, 1536, 0, 1);
  k_mlp8<<<dim3(48, 2), 256, 0, stream>>>(W_m2, b_m2, hid, pr, 1536, 768, 768, 0, 0);
  k_topk<<<NB, 256, 0, stream>>>(pr, idx);
  k_fold<<<dim3(KS, NB), 256, 0, stream>>>(idx, Y1, Wq, bq, Wk, bk, Wv, bv, Aq, biasq);
  k_gather_wo<<<dim3(96, NB), 256, 0, stream>>>(idx, Wo, WoS);

  // qkv: [1152,768] x [768,4096]^T(from xT[4096,768])
  gemm_bt<0><<<dim3(32, 9, NB), 256, 0, stream>>>(
      Aq, xT, (size_t)1152 * NC, (size_t)NPX * NC, NC, NC, NC, 1, biasq, nullptr, qk, vT, 0.f);
  // S = q @ k^T * K^-0.5, split-K=4 -> fp32 partials
  gemm_bt<1><<<dim3(3, 3, NB * 4), 256, 0, stream>>>(
      qk, qk + (size_t)KS * NPX, (size_t)768 * NPX, (size_t)768 * NPX, NPX, NPX, NPX, 4,
      nullptr, Sp, nullptr, nullptr, 0.05103103630798287f);
  k_softmax<<<dim3(KS, NB), 128, 0, stream>>>(Sp, At);
  // M = WoSel @ attn   (via At = attn^T)
  gemm_bt<2><<<dim3(3, 6, NB), 256, 0, stream>>>(
      WoS, At, (size_t)NC * KS, (size_t)KS * KS, KS, KS, KS, 1, nullptr, nullptr, Mm, nullptr, 0.f);
  // out = M @ v + bo   (via vT)
  gemm_bt<3><<<dim3(32, 6, NB), 256, 0, stream>>>(
      Mm, vT, (size_t)NC * KS, (size_t)NPX * KS, KS, KS, KS, 1, bo, out, nullptr, nullptr, 0.f);
}